// Round 4
// baseline (121.751 us; speedup 1.0000x reference)
//
#include <hip/hip_runtime.h>
#include <hip/hip_bf16.h>

// GAT layer, N=8192, IN_F=256, OUT_F=64.
// k1 gat_pre : h = input@W; f1=(h@a1)*log2e, f2=(h@a2)*log2e; h packed bf16.
// k2 gat_main: grid (512 x 4 quarters), 256 thr. K-loop vmem = staging ONLY:
//   adj tiles (16x128 int, depth-3 ring, pre-swizzled global src + XOR-swz
//   reads) and hp tiles (128x64 bf16, depth-2 ring) via global_load_lds;
//   f2 quarter in LDS. Counted s_waitcnt vmcnt(2) + raw s_barrier (T3/T4) —
//   loads stay in flight across barriers. p = exp2(lrelu(f1'+f2')-shift'),
//   shift' = lrelu(f1'+Fmax') (monotone lrelu => arg<=0, shared shift so
//   quarter-partials combine exactly). Partial num/den -> ws.
// k3 gat_fin : combine 4 partials, normalize, ELU.

using short8 = __attribute__((ext_vector_type(8))) short;
using f32x4  = __attribute__((ext_vector_type(4))) float;

#define NN     8192
#define INF_   256
#define OUTF   64
#define LR_A   0.2f
#define LOG2E  1.4426950408889634f
#define ROWS   16
#define TILE_C 128
#define CQW    2048
#define NTILES (CQW / TILE_C)   // 16
#define ADJSLOT 8192            // 16 rows * 512 B
#define HPSLOT  16384           // 128 cols * 64 feats * 2 B

__device__ __forceinline__ unsigned short f2bf_rne(float x) {
  unsigned int u = __float_as_uint(x);
  u += 0x7FFFu + ((u >> 16) & 1u);
  return (unsigned short)(u >> 16);
}

// ---------------- kernel 1: h (packed bf16), f1', f2' ----------------
__global__ __launch_bounds__(256) void gat_pre(
    const float* __restrict__ input, const float* __restrict__ W,
    const float* __restrict__ a, unsigned short* __restrict__ hp,
    float* __restrict__ f1, float* __restrict__ f2) {
  __shared__ float WT[OUTF][260];
  int tid = threadIdx.x;
  for (int idx = tid; idx < INF_ * OUTF; idx += 256) {
    int c = idx >> 6, f = idx & 63;
    WT[f][c] = W[idx];
  }
  __syncthreads();
  int w = tid >> 6, l = tid & 63;               // lane = output feature
  int i0 = blockIdx.x * 16 + w * 4;
  const float4* r0 = (const float4*)(input + (long)(i0 + 0) * INF_);
  const float4* r1 = (const float4*)(input + (long)(i0 + 1) * INF_);
  const float4* r2 = (const float4*)(input + (long)(i0 + 2) * INF_);
  const float4* r3 = (const float4*)(input + (long)(i0 + 3) * INF_);
  float h0 = 0.f, h1 = 0.f, h2 = 0.f, h3 = 0.f;
#pragma unroll 4
  for (int c4 = 0; c4 < INF_ / 4; ++c4) {
    float4 wv = *(const float4*)&WT[l][c4 * 4];
    float4 v0 = r0[c4], v1 = r1[c4], v2 = r2[c4], v3 = r3[c4];
    h0 = fmaf(v0.x, wv.x, h0); h0 = fmaf(v0.y, wv.y, h0);
    h0 = fmaf(v0.z, wv.z, h0); h0 = fmaf(v0.w, wv.w, h0);
    h1 = fmaf(v1.x, wv.x, h1); h1 = fmaf(v1.y, wv.y, h1);
    h1 = fmaf(v1.z, wv.z, h1); h1 = fmaf(v1.w, wv.w, h1);
    h2 = fmaf(v2.x, wv.x, h2); h2 = fmaf(v2.y, wv.y, h2);
    h2 = fmaf(v2.z, wv.z, h2); h2 = fmaf(v2.w, wv.w, h2);
    h3 = fmaf(v3.x, wv.x, h3); h3 = fmaf(v3.y, wv.y, h3);
    h3 = fmaf(v3.z, wv.z, h3); h3 = fmaf(v3.w, wv.w, h3);
  }
  float a1k = a[l], a2k = a[OUTF + l];
  float hh[4] = {h0, h1, h2, h3};
#pragma unroll
  for (int r = 0; r < 4; ++r) {
    int i = i0 + r;
    float t1 = hh[r] * a1k, t2 = hh[r] * a2k;
#pragma unroll
    for (int off = 32; off; off >>= 1) {
      t1 += __shfl_xor(t1, off);
      t2 += __shfl_xor(t2, off);
    }
    // packed: granule = (K32*4 + nb)*64 + g_i*16 + (feat&15), elem = i&7
    int gran = (((i >> 5) * 4) + (l >> 4)) * 64 + ((i >> 3) & 3) * 16 + (l & 15);
    hp[(long)gran * 8 + (i & 7)] = f2bf_rne(hh[r]);
    if (l == 0) { f1[i] = t1 * LOG2E; f2[i] = t2 * LOG2E; }
  }
}

// ---------------- kernel 2: fused attention (partial over col quarter) ------
__global__ __launch_bounds__(256, 2) void gat_main(
    const int* __restrict__ adj, const unsigned short* __restrict__ hp,
    const float* __restrict__ f1, const float* __restrict__ f2,
    float* __restrict__ numP, float* __restrict__ denP) {
  __shared__ __align__(16) char adjS[3 * ADJSLOT];   // 24 KB, depth-3 ring
  __shared__ __align__(16) char hpS[2 * HPSLOT];     // 32 KB, depth-2 ring
  __shared__ float f2s[CQW];                         // 8 KB
  __shared__ float ssum[4][ROWS];
  __shared__ float f1s[ROWS], shifts[ROWS], red[4];
  int tid = threadIdx.x;
  int w = tid >> 6, l = tid & 63;
  int i0 = blockIdx.x * ROWS;
  int cq = blockIdx.y;

  // global max of f2' (shift must be column-global) + stage quarter into LDS
  float fm = -1e30f;
  for (int jj = tid * 4; jj < NN; jj += 1024) {
    float4 v = *(const float4*)(f2 + jj);
    fm = fmaxf(fm, fmaxf(fmaxf(v.x, v.y), fmaxf(v.z, v.w)));
  }
  for (int jj = tid * 4; jj < CQW; jj += 1024)
    *(float4*)&f2s[jj] = *(const float4*)(f2 + cq * CQW + jj);
#pragma unroll
  for (int off = 32; off; off >>= 1) fm = fmaxf(fm, __shfl_xor(fm, off));
  if (l == 0) red[w] = fm;
  __syncthreads();
  if (tid == 0) red[0] = fmaxf(fmaxf(red[0], red[1]), fmaxf(red[2], red[3]));
  __syncthreads();
  float Fmax = red[0];
  if (tid < ROWS) {
    float v = f1[i0 + tid];
    f1s[tid] = v;
    float s = v + Fmax;
    shifts[tid] = fmaxf(s, LR_A * s);
  }
  __syncthreads();                                // full drain before pipeline

  int q = l & 15, g = l >> 4;
  float f1r = f1s[q], sh = shifts[q];
  float u1 = f1r - sh, u2 = LR_A * f1r - sh;
  f32x4 acc0 = {0.f, 0.f, 0.f, 0.f}, acc1 = acc0, acc2 = acc0, acc3 = acc0;
  float srow = 0.f;

  // stage adj tile t -> slot: 2 insts/wave, 2 rows each. Global src pre-
  // swizzled (unit' = unit ^ (row&7)) so linear LDS dest reads conflict-light.
  auto stage_adj = [&](int t, int slot) {
#pragma unroll
    for (int j = 0; j < 2; ++j) {
      int rr = w * 4 + j * 2 + (l >> 5);
      const int* src = adj + (long)(i0 + rr) * NN + cq * CQW + t * TILE_C
                       + (((l & 31) ^ (rr & 7)) << 2);
      char* d = adjS + slot * ADJSLOT + (w * 4 + j * 2) * 512;
      __builtin_amdgcn_global_load_lds(
          (const __attribute__((address_space(1))) void*)src,
          (__attribute__((address_space(3))) void*)d, 16, 0, 0);
    }
  };
  // stage hp tile t -> slot: 4 insts/wave, wave w stages its own K32-step
  auto stage_hp = [&](int t, int slot) {
    const unsigned short* base = hp + (long)(cq * 64 + t * 4 + w) * 2048 + l * 8;
#pragma unroll
    for (int j = 0; j < 4; ++j) {
      const unsigned short* src = base + j * 512;
      char* d = hpS + slot * HPSLOT + w * 4096 + j * 1024;
      __builtin_amdgcn_global_load_lds(
          (const __attribute__((address_space(1))) void*)src,
          (__attribute__((address_space(3))) void*)d, 16, 0, 0);
    }
  };

  // prologue: issue order matters for the vmcnt FIFO accounting below
  stage_hp(0, 0);
  stage_adj(0, 0);
  stage_adj(1, 1);

  for (int t = 0; t < NTILES; ++t) {
    // FIFO at this point: [adj(t):2][hp(t):4][adj(t+1):2] -> vmcnt(2)
    // retires exactly {adj(t), hp(t)}. Tail iteration drains all.
    if (t < NTILES - 1) {
      asm volatile("s_waitcnt vmcnt(2)" ::: "memory");
    } else {
      asm volatile("s_waitcnt vmcnt(0)" ::: "memory");
    }
    __builtin_amdgcn_s_barrier();                 // raw: no vmcnt(0) drain
    if (t + 1 < NTILES) stage_hp(t + 1, (t + 1) & 1);
    if (t + 2 < NTILES) stage_adj(t + 2, (t + 2) % 3);

    // ---- consume tile t (LDS only) ----
    const char* ab = adjS + (t % 3) * ADJSLOT + q * 512;
    int koff = w * 128 + g * 32;
    int sw = (q & 7) << 4;
    int4 A0 = *(const int4*)(ab + (koff ^ sw));
    int4 A1 = *(const int4*)(ab + ((koff + 16) ^ sw));
    const float* f2b = f2s + t * TILE_C + w * 32 + g * 8;
    float4 F0 = *(const float4*)(f2b);
    float4 F1 = *(const float4*)(f2b + 4);
    float fa[8] = {F0.x, F0.y, F0.z, F0.w, F1.x, F1.y, F1.z, F1.w};
    int   aa[8] = {A0.x, A0.y, A0.z, A0.w, A1.x, A1.y, A1.z, A1.w};

    union { short8 v; unsigned short u[8]; } pa;
    float ps = 0.f;
#pragma unroll
    for (int e = 0; e < 8; ++e) {
      float arg = fmaxf(u1 + fa[e], fmaf(LR_A, fa[e], u2));
      float pe = (aa[e] > 0) ? exp2f(arg) : 0.f;
      ps += pe;
      pa.u[e] = f2bf_rne(pe);
    }
    srow += ps;

    const unsigned short* hb =
        (const unsigned short*)(hpS + (t & 1) * HPSLOT + w * 4096) + l * 8;
    short8 b0 = *(const short8*)(hb + 0 * 512);
    short8 b1 = *(const short8*)(hb + 1 * 512);
    short8 b2 = *(const short8*)(hb + 2 * 512);
    short8 b3 = *(const short8*)(hb + 3 * 512);
    acc0 = __builtin_amdgcn_mfma_f32_16x16x32_bf16(pa.v, b0, acc0, 0, 0, 0);
    acc1 = __builtin_amdgcn_mfma_f32_16x16x32_bf16(pa.v, b1, acc1, 0, 0, 0);
    acc2 = __builtin_amdgcn_mfma_f32_16x16x32_bf16(pa.v, b2, acc2, 0, 0, 0);
    acc3 = __builtin_amdgcn_mfma_f32_16x16x32_bf16(pa.v, b3, acc3, 0, 0, 0);
  }

  // row sums: combine the 4 k-groups (lanes q, q+16, q+32, q+48)
  srow += __shfl_xor(srow, 16);
  srow += __shfl_xor(srow, 32);

  __syncthreads();                                // loop done; reuse hpS
  if (l < ROWS) ssum[w][l] = srow;
  float* accs = (float*)hpS;                      // [4][16][64]
#pragma unroll
  for (int r = 0; r < 4; ++r) {
    accs[(w * ROWS + g * 4 + r) * OUTF + 0 * 16 + q] = acc0[r];
    accs[(w * ROWS + g * 4 + r) * OUTF + 1 * 16 + q] = acc1[r];
    accs[(w * ROWS + g * 4 + r) * OUTF + 2 * 16 + q] = acc2[r];
    accs[(w * ROWS + g * 4 + r) * OUTF + 3 * 16 + q] = acc3[r];
  }
  __syncthreads();

  for (int idx = tid; idx < ROWS * OUTF; idx += 256) {
    int m = idx >> 6, n = idx & 63;
    float num = 0.f, den = 0.f;
#pragma unroll
    for (int ww = 0; ww < 4; ++ww) {
      num += accs[(ww * ROWS + m) * OUTF + n];
      den += ssum[ww][m];
    }
    numP[((long)cq * NN + i0 + m) * OUTF + n] = num;
    if (n == 0) denP[(long)cq * NN + i0 + m] = den;
  }
}

// ---------------- kernel 3: combine quarters, normalize, ELU ----------------
__global__ __launch_bounds__(256) void gat_fin(
    const float* __restrict__ numP, const float* __restrict__ denP,
    float* __restrict__ out) {
  int gid = blockIdx.x * 256 + threadIdx.x;
  int row = gid >> 6, n = gid & 63;
  float num = 0.f, den = 0.f;
#pragma unroll
  for (int c = 0; c < 4; ++c) {
    num += numP[((long)c * NN + row) * OUTF + n];
    den += denP[(long)c * NN + row];
  }
  float v = num / den;
  out[gid] = v > 0.f ? v : expm1f(v);
}

extern "C" void kernel_launch(void* const* d_in, const int* in_sizes, int n_in,
                              void* d_out, int out_size, void* d_ws, size_t ws_size,
                              hipStream_t stream) {
  const float* input = (const float*)d_in[0];
  const int*   adj   = (const int*)d_in[1];
  const float* W     = (const float*)d_in[2];
  const float* a     = (const float*)d_in[3];
  float* out = (float*)d_out;
  char* ws = (char*)d_ws;
  unsigned short* hp = (unsigned short*)ws;             // 1 MB packed bf16 h
  float* f1   = (float*)(ws + (1 << 20));               // 32 KB
  float* f2   = (float*)(ws + (1 << 20) + (32 << 10));  // 32 KB
  float* numP = (float*)(ws + (1 << 20) + (64 << 10));  // 8 MB [4][8192][64]
  float* denP = (float*)(ws + (1 << 20) + (64 << 10) + (8 << 20)); // 128 KB
  (void)in_sizes; (void)n_in; (void)out_size; (void)ws_size;

  gat_pre<<<512, 256, 0, stream>>>(input, W, a, hp, f1, f2);
  gat_main<<<dim3(512, 4), 256, 0, stream>>>(adj, hp, f1, f2, numP, denP);
  gat_fin<<<NN * OUTF / 256, 256, 0, stream>>>(numP, denP, out);
}